// Round 14
// baseline (610.460 us; speedup 1.0000x reference)
//
#include <hip/hip_runtime.h>

typedef unsigned short u16;
typedef float f32x4 __attribute__((ext_vector_type(4)));
typedef __bf16 bf16x8 __attribute__((ext_vector_type(8)));
typedef u16 u16x8 __attribute__((ext_vector_type(8)));

// ---------- helpers ----------
__device__ __forceinline__ u16 f2bf(float f) {
  union { float f; unsigned int u; } x; x.f = f;
  unsigned int u = x.u;
  u += 0x7fffu + ((u >> 16) & 1u);            // round-to-nearest-even
  return (u16)(u >> 16);
}
__device__ __forceinline__ float bf2f(u16 h) {
  union { unsigned int u; float f; } x; x.u = ((unsigned int)h) << 16;
  return x.f;
}
#if __has_builtin(__builtin_amdgcn_exp2f)
__device__ __forceinline__ float exp2_hw(float x) { return __builtin_amdgcn_exp2f(x); }
#else
__device__ __forceinline__ float exp2_hw(float x) { return exp2f(x); }
#endif
// async global->LDS, 16B per lane. LDS dest = wave-uniform base + lane*16.
__device__ __forceinline__ void load_lds16(const void* g, void* l) {
  __builtin_amdgcn_global_load_lds(
      (const __attribute__((address_space(1))) unsigned int*)g,
      (__attribute__((address_space(3))) unsigned int*)l, 16, 0, 0);
}
__device__ __forceinline__ f32x4 mfma16(bf16x8 a, bf16x8 b, f32x4 c) {
  return __builtin_amdgcn_mfma_f32_16x16x32_bf16(a, b, c, 0, 0, 0);
}
__device__ __forceinline__ void bar() { __builtin_amdgcn_s_barrier(); }
template <int Nw> __device__ __forceinline__ void waitvm() {
  if constexpr (Nw == 8)      asm volatile("s_waitcnt vmcnt(8)" ::: "memory");
  else if constexpr (Nw == 6) asm volatile("s_waitcnt vmcnt(6)" ::: "memory");
  else if constexpr (Nw == 4) asm volatile("s_waitcnt vmcnt(4)" ::: "memory");
  else                        asm volatile("s_waitcnt vmcnt(0)" ::: "memory");
}
// Phase brackets (R5/R6 skeleton — best measured).
__device__ __forceinline__ void phase_open() {
  asm volatile("" ::: "memory");
  __builtin_amdgcn_s_barrier();
  asm volatile("" ::: "memory");
  __builtin_amdgcn_s_setprio(1);
}
__device__ __forceinline__ void phase_close() {
  __builtin_amdgcn_s_setprio(0);
  asm volatile("" ::: "memory");
  __builtin_amdgcn_s_barrier();
  asm volatile("" ::: "memory");
}
template <int NV> __device__ __forceinline__ void phase_close_vm() {
  __builtin_amdgcn_s_setprio(0);
  asm volatile("" ::: "memory");
  waitvm<NV>();                 // counted drain BEFORE the barrier -> collective
  __builtin_amdgcn_s_barrier();
  asm volatile("" ::: "memory");
}

// ---------- prep kernels (R13 vectorized versions) ----------
__global__ void convert4(const float* __restrict__ in, u16* __restrict__ out) {
  int i = blockIdx.x * blockDim.x + threadIdx.x;
  float4 v = reinterpret_cast<const float4*>(in)[i];
  ushort4 o;
  o.x = f2bf(v.x); o.y = f2bf(v.y); o.z = f2bf(v.z); o.w = f2bf(v.w);
  reinterpret_cast<ushort4*>(out)[i] = o;
}

// in: [R][Cd] fp32 -> out: [Cd][R] bf16. 64x64 tile, 256 threads, 16B ops.
__global__ __launch_bounds__(256) void transpose_f32_bf16(const float* __restrict__ in,
                                                          u16* __restrict__ out,
                                                          int R, int Cd) {
  __shared__ float tile[64][65];
  int c0 = blockIdx.x * 64, r0 = blockIdx.y * 64;
  int tid = threadIdx.x;
  int c4 = tid & 15, rr = tid >> 4;
#pragma unroll
  for (int p = 0; p < 4; ++p) {
    float4 v = *reinterpret_cast<const float4*>(
        in + (size_t)(r0 + rr + 16 * p) * Cd + c0 + c4 * 4);
    tile[rr + 16 * p][c4 * 4 + 0] = v.x;
    tile[rr + 16 * p][c4 * 4 + 1] = v.y;
    tile[rr + 16 * p][c4 * 4 + 2] = v.z;
    tile[rr + 16 * p][c4 * 4 + 3] = v.w;
  }
  __syncthreads();
  int rx8 = tid & 7, cr = tid >> 3;
#pragma unroll
  for (int p = 0; p < 2; ++p) {
    int c = cr + 32 * p;
    u16x8 o;
#pragma unroll
    for (int k = 0; k < 8; ++k) o[k] = f2bf(tile[rx8 * 8 + k][c]);
    *reinterpret_cast<u16x8*>(out + (size_t)(c0 + c) * R + r0 + rx8 * 8) = o;
  }
}

// rope table: [2048][64] of (cos, sin)
__global__ void rope_table(float2* __restrict__ tab) {
  int i = blockIdx.x * blockDim.x + threadIdx.x;   // 2048*64
  int s = i >> 6, d2 = i & 63;
  float inv = powf(10000.f, -(float)d2 * (1.f / 64.f));
  float fr = (float)s * inv;
  tab[i] = make_float2(cosf(fr), sinf(fr));
}

// in-place rope, vectorized 16B (R13).
__global__ __launch_bounds__(256) void rope_apply(u16* __restrict__ qkv,
                                                  const float2* __restrict__ tab) {
  int i = blockIdx.x * blockDim.x + threadIdx.x;   // 4096*40*8
  int g = i & 7;
  int head = (i >> 3) % 40;
  int row = i / 320;
  size_t base = (size_t)row * 6144 + head * 128 + g * 8;
  u16x8 a = *reinterpret_cast<const u16x8*>(qkv + base);
  u16x8 b = *reinterpret_cast<const u16x8*>(qkv + base + 64);
  const float2* cs = tab + (row & 2047) * 64 + g * 8;
  float sc = (head < 32) ? 0.12751731654059898f : 1.f;  // log2e/sqrt(128)
  u16x8 o1, o2;
#pragma unroll
  for (int q = 0; q < 8; ++q) {
    float t1 = bf2f(a[q]), t2 = bf2f(b[q]);
    float2 c2 = cs[q];
    o1[q] = f2bf((t1 * c2.x - t2 * c2.y) * sc);
    o2[q] = f2bf((t1 * c2.y + t2 * c2.x) * sc);
  }
  *reinterpret_cast<u16x8*>(qkv + base) = o1;
  *reinterpret_cast<u16x8*>(qkv + base + 64) = o2;
}

// vT[b][hkv][d][s_perm] <- qkv[b*2048+s][5120 + hkv*128 + d]
__global__ void build_vT(const u16* __restrict__ qkv, u16* __restrict__ vT) {
  __shared__ u16 tile[32][33];
  int st = blockIdx.x, dt = blockIdx.y, bh = blockIdx.z;  // bh = b*8+hkv
  int b = bh >> 3, hkv = bh & 7;
  int tx = threadIdx.x, ty = threadIdx.y;
  int s0 = st * 32, d0 = dt * 32;
#pragma unroll
  for (int i = 0; i < 4; ++i)
    tile[ty + 8 * i][tx] =
        qkv[(size_t)(b * 2048 + s0 + ty + 8 * i) * 6144 + 5120 + hkv * 128 + d0 + tx];
  __syncthreads();
  int s = s0 + tx;
  int sl = s & 63;
  int sp = (s & ~63) | (sl & 0x23) | ((sl & 0x0C) << 1) | ((sl & 0x10) >> 2);
#pragma unroll
  for (int i = 0; i < 4; ++i)
    vT[((size_t)bh * 128 + d0 + ty + 8 * i) * 2048 + sp] = tile[tx][ty + 8 * i];
}

// ---------- GEMM g3 (qkv): 128x256, dbuf-2, 4 phases/K-tile ----------
// The g2 phase skeleton with BM=128, BN=256 -> grid 32x24 = 768 = 3 full CU
// rounds. 8 waves 2M x 4N (wave 64x64). Per K-tile batch = 6 loads (A:2,B:4).
// Staging ledger (all of batch t+2 -> CURRENT buf c = t&1 = (t+2)&1):
//   Bh0(rows 0-127)@P2   (all waves' B reads retired by P1-close)
//   Bh1(rows128-255)+A@P3 (A reads retired by P2-close)
// vmcnt(6) at P3-close drains batch t+1 (leaves t+2's 6 in flight).
template <int OUT_BF16>
__global__ __launch_bounds__(512, 2) void gemm_g3(const u16* __restrict__ A,
                                                  const u16* __restrict__ BT,
                                                  void* __restrict__ Cv,
                                                  int M, int N, int K) {
  __shared__ u16 As[2][128][64];
  __shared__ u16 Bs[2][256][64];
  const int tid = threadIdx.x, lane = tid & 63, wave = tid >> 6;
  const int lr = lane & 15, lg = lane >> 4, l7 = lane & 7;
  const int wm = wave >> 2, wn = wave & 3;
  const int nbx = N / 256;
  int bid = blockIdx.x;
  const int cpx = (int)gridDim.x >> 3;
  bid = (bid & 7) * cpx + (bid >> 3);               // XCD swizzle (grid%8==0)
  const int bm = (bid / nbx) * 128, bn = (bid % nbx) * 256;
  const int NT = K / 64;
  const int ch0 = (lg ^ l7) << 3, ch1 = ((4 | lg) ^ l7) << 3;

  auto stageA = [&](int t, int rg) {
    int k0 = t * 64;
#pragma unroll
    for (int o = 0; o < 2; ++o) {
      int cid = o * 512 + tid;
      int row = cid >> 3;
      int sc2 = (cid & 7) ^ (row & 7);
      load_lds16(A + (size_t)(bm + row) * K + k0 + sc2 * 8,
                 (u16*)&As[rg][0][0] + (o * 512 + wave * 64) * 8);
    }
  };
  auto stageBh = [&](int t, int rg, int h) {
    int k0 = t * 64;
#pragma unroll
    for (int o = 0; o < 2; ++o) {
      int oo = h * 2 + o;
      int cid = oo * 512 + tid;
      int row = cid >> 3;
      int sc2 = (cid & 7) ^ (row & 7);
      load_lds16(BT + (size_t)(bn + row) * K + k0 + sc2 * 8,
                 (u16*)&Bs[rg][0][0] + (oo * 512 + wave * 64) * 8);
    }
  };

  bf16x8 a01[2][2], a23[2][2], b01[2][2], b23[2][2];
  f32x4 acc[4][4] = {};

  stageA(0, 0); stageBh(0, 0, 0); stageBh(0, 0, 1);
  stageA(1, 1); stageBh(1, 1, 0); stageBh(1, 1, 1);
  waitvm<6>();                 // 12 outstanding -> drain tile 0's 6
  bar();

  for (int t = 0; t < NT; ++t) {
    const int c = t & 1;
    const bool pf = (t + 2) < NT;
    // ---- P0: read A01(4) + B01(4); MFMA A01 x B01
#pragma unroll
    for (int mi = 0; mi < 2; ++mi) {
      a01[mi][0] = *(const bf16x8*)&As[c][wm * 64 + mi * 16 + lr][ch0];
      a01[mi][1] = *(const bf16x8*)&As[c][wm * 64 + mi * 16 + lr][ch1];
    }
#pragma unroll
    for (int j = 0; j < 2; ++j) {
      b01[j][0] = *(const bf16x8*)&Bs[c][wn * 64 + j * 16 + lr][ch0];
      b01[j][1] = *(const bf16x8*)&Bs[c][wn * 64 + j * 16 + lr][ch1];
    }
    phase_open();
#pragma unroll
    for (int mi = 0; mi < 2; ++mi)
#pragma unroll
      for (int j = 0; j < 2; ++j) {
        acc[mi][j] = mfma16(a01[mi][0], b01[j][0], acc[mi][j]);
        acc[mi][j] = mfma16(a01[mi][1], b01[j][1], acc[mi][j]);
      }
    phase_close();
    // ---- P1: read B23(4); MFMA A01 x B23
#pragma unroll
    for (int j = 0; j < 2; ++j) {
      b23[j][0] = *(const bf16x8*)&Bs[c][wn * 64 + (j + 2) * 16 + lr][ch0];
      b23[j][1] = *(const bf16x8*)&Bs[c][wn * 64 + (j + 2) * 16 + lr][ch1];
    }
    phase_open();
#pragma unroll
    for (int mi = 0; mi < 2; ++mi)
#pragma unroll
      for (int j = 0; j < 2; ++j) {
        acc[mi][j + 2] = mfma16(a01[mi][0], b23[j][0], acc[mi][j + 2]);
        acc[mi][j + 2] = mfma16(a01[mi][1], b23[j][1], acc[mi][j + 2]);
      }
    phase_close();
    // ---- P2: read A23(4); stage Bh0(t+2) into buf c; MFMA A23 x B01
#pragma unroll
    for (int mi = 0; mi < 2; ++mi) {
      a23[mi][0] = *(const bf16x8*)&As[c][wm * 64 + (mi + 2) * 16 + lr][ch0];
      a23[mi][1] = *(const bf16x8*)&As[c][wm * 64 + (mi + 2) * 16 + lr][ch1];
    }
    if (pf) stageBh(t + 2, c, 0);
    phase_open();
#pragma unroll
    for (int mi = 0; mi < 2; ++mi)
#pragma unroll
      for (int j = 0; j < 2; ++j) {
        acc[mi + 2][j] = mfma16(a23[mi][0], b01[j][0], acc[mi + 2][j]);
        acc[mi + 2][j] = mfma16(a23[mi][1], b01[j][1], acc[mi + 2][j]);
      }
    phase_close();
    // ---- P3: stage Bh1(t+2)+A(t+2); MFMA A23 x B23; vmcnt(6)
    if (pf) { stageBh(t + 2, c, 1); stageA(t + 2, c); }
    phase_open();
#pragma unroll
    for (int mi = 0; mi < 2; ++mi)
#pragma unroll
      for (int j = 0; j < 2; ++j) {
        acc[mi + 2][j + 2] = mfma16(a23[mi][0], b23[j][0], acc[mi + 2][j + 2]);
        acc[mi + 2][j + 2] = mfma16(a23[mi][1], b23[j][1], acc[mi + 2][j + 2]);
      }
    if (pf) phase_close_vm<6>(); else phase_close_vm<0>();
  }
#pragma unroll
  for (int mi = 0; mi < 4; ++mi) {
    int row = bm + wm * 64 + mi * 16 + lg * 4;
#pragma unroll
    for (int j = 0; j < 4; ++j) {
      int col = bn + wn * 64 + j * 16 + lr;
#pragma unroll
      for (int r = 0; r < 4; ++r) {
        if constexpr (OUT_BF16)
          ((u16*)Cv)[(size_t)(row + r) * N + col] = f2bf(acc[mi][j][r]);
        else
          ((float*)Cv)[(size_t)(row + r) * N + col] = acc[mi][j][r];
      }
    }
  }
}

// ---------- GEMM2 (out-proj): 256x256, dbuf-2, 4 phases/K-tile ----------
// R5/R6 measured config. stage(t+2) -> CURRENT buffer after barrier-retired
// reads (Bh0@P2, Bh1+A@P3); vmcnt(8) at P3-close drains stage(t+1).
template <int OUT_BF16>
__global__ __launch_bounds__(512, 2) void gemm_g2(const u16* __restrict__ A,
                                                  const u16* __restrict__ BT,
                                                  void* __restrict__ Cv,
                                                  int M, int N, int K) {
  __shared__ u16 As[2][256][64];
  __shared__ u16 Bs[2][256][64];
  const int tid = threadIdx.x, lane = tid & 63, wave = tid >> 6;
  const int lr = lane & 15, lg = lane >> 4, l7 = lane & 7;
  const int wm = wave >> 2, wn = wave & 3;
  const int nbx = N / 256;
  int bid = blockIdx.x;
  const int cpx = (int)gridDim.x >> 3;
  bid = (bid & 7) * cpx + (bid >> 3);
  const int bm = (bid / nbx) * 256, bn = (bid % nbx) * 256;
  const int NT = K / 64;
  const int ch0 = (lg ^ l7) << 3, ch1 = ((4 | lg) ^ l7) << 3;

  auto stageA = [&](int t, int rg) {
    int k0 = t * 64;
#pragma unroll
    for (int o = 0; o < 4; ++o) {
      int cid = o * 512 + tid;
      int row = cid >> 3;
      int sc2 = (cid & 7) ^ (row & 7);
      load_lds16(A + (size_t)(bm + row) * K + k0 + sc2 * 8,
                 (u16*)&As[rg][0][0] + (o * 512 + wave * 64) * 8);
    }
  };
  auto stageBh = [&](int t, int rg, int h) {
    int k0 = t * 64;
#pragma unroll
    for (int o = 0; o < 2; ++o) {
      int oo = h * 2 + o;
      int cid = oo * 512 + tid;
      int row = cid >> 3;
      int sc2 = (cid & 7) ^ (row & 7);
      load_lds16(BT + (size_t)(bn + row) * K + k0 + sc2 * 8,
                 (u16*)&Bs[rg][0][0] + (oo * 512 + wave * 64) * 8);
    }
  };

  bf16x8 a0[4][2], a1[4][2], b01[2][2], b23[2][2];
  f32x4 acc[8][4] = {};

  stageA(0, 0); stageBh(0, 0, 0); stageBh(0, 0, 1); stageA(1, 1);
  stageBh(1, 1, 0); stageBh(1, 1, 1);
  waitvm<8>();
  bar();

  for (int t = 0; t < NT; ++t) {
    const int c = t & 1;
    const bool pf = (t + 2) < NT;
    // ---- P0: read A0(8) + B01(4); MFMA A0 x B01
#pragma unroll
    for (int mi = 0; mi < 4; ++mi) {
      a0[mi][0] = *(const bf16x8*)&As[c][wm * 128 + mi * 16 + lr][ch0];
      a0[mi][1] = *(const bf16x8*)&As[c][wm * 128 + mi * 16 + lr][ch1];
    }
#pragma unroll
    for (int j = 0; j < 2; ++j) {
      b01[j][0] = *(const bf16x8*)&Bs[c][wn * 64 + j * 16 + lr][ch0];
      b01[j][1] = *(const bf16x8*)&Bs[c][wn * 64 + j * 16 + lr][ch1];
    }
    phase_open();
#pragma unroll
    for (int mi = 0; mi < 4; ++mi)
#pragma unroll
      for (int j = 0; j < 2; ++j) {
        acc[mi][j] = mfma16(a0[mi][0], b01[j][0], acc[mi][j]);
        acc[mi][j] = mfma16(a0[mi][1], b01[j][1], acc[mi][j]);
      }
    phase_close();
    // ---- P1: read B23(4); MFMA A0 x B23
#pragma unroll
    for (int j = 0; j < 2; ++j) {
      b23[j][0] = *(const bf16x8*)&Bs[c][wn * 64 + (j + 2) * 16 + lr][ch0];
      b23[j][1] = *(const bf16x8*)&Bs[c][wn * 64 + (j + 2) * 16 + lr][ch1];
    }
    phase_open();
#pragma unroll
    for (int mi = 0; mi < 4; ++mi)
#pragma unroll
      for (int j = 0; j < 2; ++j) {
        acc[mi][j + 2] = mfma16(a0[mi][0], b23[j][0], acc[mi][j + 2]);
        acc[mi][j + 2] = mfma16(a0[mi][1], b23[j][1], acc[mi][j + 2]);
      }
    phase_close();
    // ---- P2: read A1(8); stage Bh0(t+2); MFMA A1 x B01
#pragma unroll
    for (int mi = 0; mi < 4; ++mi) {
      a1[mi][0] = *(const bf16x8*)&As[c][wm * 128 + 64 + mi * 16 + lr][ch0];
      a1[mi][1] = *(const bf16x8*)&As[c][wm * 128 + 64 + mi * 16 + lr][ch1];
    }
    if (pf) stageBh(t + 2, c, 0);
    phase_open();
#pragma unroll
    for (int mi = 0; mi < 4; ++mi)
#pragma unroll
      for (int j = 0; j < 2; ++j) {
        acc[mi + 4][j] = mfma16(a1[mi][0], b01[j][0], acc[mi + 4][j]);
        acc[mi + 4][j] = mfma16(a1[mi][1], b01[j][1], acc[mi + 4][j]);
      }
    phase_close();
    // ---- P3: stage Bh1(t+2)+A(t+2); MFMA A1 x B23; vmcnt(8)
    if (pf) { stageBh(t + 2, c, 1); stageA(t + 2, c); }
    phase_open();
#pragma unroll
    for (int mi = 0; mi < 4; ++mi)
#pragma unroll
      for (int j = 0; j < 2; ++j) {
        acc[mi + 4][j + 2] = mfma16(a1[mi][0], b23[j][0], acc[mi + 4][j + 2]);
        acc[mi + 4][j + 2] = mfma16(a1[mi][1], b23[j][1], acc[mi + 4][j + 2]);
      }
    if (pf) phase_close_vm<8>(); else phase_close_vm<0>();
  }
#pragma unroll
  for (int mi = 0; mi < 8; ++mi) {
    int row = bm + wm * 128 + mi * 16 + lg * 4;
#pragma unroll
    for (int j = 0; j < 4; ++j) {
      int col = bn + wn * 64 + j * 16 + lr;
#pragma unroll
      for (int r = 0; r < 4; ++r) {
        if constexpr (OUT_BF16)
          ((u16*)Cv)[(size_t)(row + r) * N + col] = f2bf(acc[mi][j][r]);
        else
          ((float*)Cv)[(size_t)(row + r) * N + col] = acc[mi][j][r];
      }
    }
  }
}

// ---------- flash attention (no-max softmax, in-register P) ----------
// R6 version (best measured). grid (16,32,2), 4 waves; wave owns 32 q-rows.
__global__ __launch_bounds__(256, 3) void attn_fused(const u16* __restrict__ qkv,
                                                     const u16* __restrict__ vT,
                                                     u16* __restrict__ attn_out) {
  __shared__ u16 Ksm[64][128];    // [kv][d]  16 chunks/row, XOR-swizzled
  __shared__ u16 Vsm[128][64];    // [d][kv]   8 chunks/row, XOR-swizzled
  const int qt = blockIdx.x, h = blockIdx.y, b = blockIdx.z;
  const int hkv = h >> 2;
  const int tid = threadIdx.x, lane = tid & 63, wave = tid >> 6;
  const int lr = lane & 15, lg = lane >> 4;
  const int qrow0 = qt * 128 + wave * 32;

  bf16x8 qf[2][4];
#pragma unroll
  for (int q2 = 0; q2 < 2; ++q2) {
    const u16* qp = qkv + (size_t)(b * 2048 + qrow0 + q2 * 16 + lr) * 6144 + h * 128;
#pragma unroll
    for (int kk = 0; kk < 4; ++kk)
      qf[q2][kk] = *(const bf16x8*)(qp + kk * 32 + lg * 8);
  }
  float l_acc[2] = {0.f, 0.f};
  f32x4 acc_o[2][8] = {};

  for (int kv0 = 0; kv0 < 2048; kv0 += 64) {
#pragma unroll
    for (int c = 0; c < 4; ++c) {
      int cid = c * 256 + tid;
      int base = (c * 256 + wave * 64) * 8;
      int krow = cid >> 4;
      int kcc = (cid & 15) ^ (krow & 7);
      load_lds16(qkv + (size_t)(b * 2048 + kv0 + krow) * 6144 + 4096 + hkv * 128 + kcc * 8,
                 (u16*)Ksm + base);
      int vrow = cid >> 3;
      int vcc = (cid & 7) ^ (vrow & 7);
      load_lds16(vT + ((size_t)(b * 8 + hkv) * 128 + vrow) * 2048 + kv0 + vcc * 8,
                 (u16*)Vsm + base);
    }
    __syncthreads();

    bf16x8 pfr[2][2];
#pragma unroll
    for (int k2 = 0; k2 < 2; ++k2) {
      f32x4 sc[2][2] = {};
#pragma unroll
      for (int ktl = 0; ktl < 2; ++ktl) {
        int krow = (k2 * 2 + ktl) * 16 + lr;
#pragma unroll
        for (int kk = 0; kk < 4; ++kk) {
          bf16x8 kf = *(const bf16x8*)((u16*)Ksm + krow * 128 +
                                       ((((kk << 2) | lg) ^ (krow & 7)) << 3));
          sc[0][ktl] = mfma16(kf, qf[0][kk], sc[0][ktl]);
          sc[1][ktl] = mfma16(kf, qf[1][kk], sc[1][ktl]);
        }
      }
#pragma unroll
      for (int q2 = 0; q2 < 2; ++q2) {
        bf16x8 pk;
#pragma unroll
        for (int ktl = 0; ktl < 2; ++ktl)
#pragma unroll
          for (int r = 0; r < 4; ++r) {
            float e = exp2_hw(sc[q2][ktl][r]);
            l_acc[q2] += e;
            pk[ktl * 4 + r] = (__bf16)e;
          }
        pfr[q2][k2] = pk;
      }
    }
#pragma unroll
    for (int dt = 0; dt < 8; ++dt) {
      int vrow = dt * 16 + lr;
#pragma unroll
      for (int k2 = 0; k2 < 2; ++k2) {
        bf16x8 vf = *(const bf16x8*)((u16*)Vsm + vrow * 64 +
                                     ((((k2 << 2) | lg) ^ (vrow & 7)) << 3));
        acc_o[0][dt] = mfma16(pfr[0][k2], vf, acc_o[0][dt]);
        acc_o[1][dt] = mfma16(pfr[1][k2], vf, acc_o[1][dt]);
      }
    }
    __syncthreads();
  }
#pragma unroll
  for (int q2 = 0; q2 < 2; ++q2) {
    float l = l_acc[q2];
    l += __shfl_xor(l, 16);
    l += __shfl_xor(l, 32);
    float li = 1.f / l;
    float linv[4];
#pragma unroll
    for (int r = 0; r < 4; ++r) linv[r] = __shfl(li, lg * 4 + r);
    u16* op = attn_out + (size_t)(b * 2048 + qrow0 + q2 * 16) * 4096 + h * 128;
#pragma unroll
    for (int dt = 0; dt < 8; ++dt)
#pragma unroll
      for (int r = 0; r < 4; ++r)
        op[(size_t)(lg * 4 + r) * 4096 + dt * 16 + lr] = f2bf(acc_o[q2][dt][r] * linv[r]);
  }
}

// ---------- launch ----------
extern "C" void kernel_launch(void* const* d_in, const int* in_sizes, int n_in,
                              void* d_out, int out_size, void* d_ws, size_t ws_size,
                              hipStream_t stream) {
  const float* x     = (const float*)d_in[0];   // [2][2048][4096]
  const float* w_qkv = (const float*)d_in[1];   // [4096][6144]
  const float* w_out = (const float*)d_in[2];   // [4096][4096]
  float* out = (float*)d_out;                   // [4096][4096] fp32
  char* ws = (char*)d_ws;

  u16*    xbf = (u16*)(ws);                         // 32MB; later reused as attn_out
  u16*    wT  = (u16*)(ws + (size_t)33554432);      // 48MB; wqkvT then woutT
  u16*    qkv = (u16*)(ws + (size_t)83886080);      // 48MB
  u16*    vT  = (u16*)(ws + (size_t)134217728);     // 8MB
  float2* tab = (float2*)(ws + (size_t)142606336);  // 1MB

  dim3 tb(32, 8);
  convert4<<<16384, 256, 0, stream>>>(x, xbf);
  transpose_f32_bf16<<<dim3(96, 64), 256, 0, stream>>>(w_qkv, wT, 4096, 6144);
  rope_table<<<512, 256, 0, stream>>>(tab);
  // qkv = xbf @ wT^T : M=4096, N=6144, K=4096.  768 wgs = 3 full CU rounds
  gemm_g3<1><<<768, 512, 0, stream>>>(xbf, wT, qkv, 4096, 6144, 4096);
  rope_apply<<<5120, 256, 0, stream>>>(qkv, tab);
  build_vT<<<dim3(64, 4, 16), tb, 0, stream>>>(qkv, vT);
  attn_fused<<<dim3(16, 32, 2), 256, 0, stream>>>(qkv, vT, xbf);
  transpose_f32_bf16<<<dim3(64, 64), 256, 0, stream>>>(w_out, wT, 4096, 4096);
  // out = attn @ woutT^T : M=N=K=4096.  256 wgs = exactly 1 round
  gemm_g2<0><<<256, 512, 0, stream>>>(xbf, wT, out, 4096, 4096, 4096);
}

// Round 15
// 578.863 us; speedup vs baseline: 1.0546x; 1.0546x over previous
//
#include <hip/hip_runtime.h>

typedef unsigned short u16;
typedef float f32x4 __attribute__((ext_vector_type(4)));
typedef __bf16 bf16x8 __attribute__((ext_vector_type(8)));
typedef u16 u16x8 __attribute__((ext_vector_type(8)));

// ---------- helpers ----------
__device__ __forceinline__ u16 f2bf(float f) {
  union { float f; unsigned int u; } x; x.f = f;
  unsigned int u = x.u;
  u += 0x7fffu + ((u >> 16) & 1u);            // round-to-nearest-even
  return (u16)(u >> 16);
}
__device__ __forceinline__ float bf2f(u16 h) {
  union { unsigned int u; float f; } x; x.u = ((unsigned int)h) << 16;
  return x.f;
}
#if __has_builtin(__builtin_amdgcn_exp2f)
__device__ __forceinline__ float exp2_hw(float x) { return __builtin_amdgcn_exp2f(x); }
#else
__device__ __forceinline__ float exp2_hw(float x) { return exp2f(x); }
#endif
// async global->LDS, 16B per lane. LDS dest = wave-uniform base + lane*16.
__device__ __forceinline__ void load_lds16(const void* g, void* l) {
  __builtin_amdgcn_global_load_lds(
      (const __attribute__((address_space(1))) unsigned int*)g,
      (__attribute__((address_space(3))) unsigned int*)l, 16, 0, 0);
}
__device__ __forceinline__ f32x4 mfma16(bf16x8 a, bf16x8 b, f32x4 c) {
  return __builtin_amdgcn_mfma_f32_16x16x32_bf16(a, b, c, 0, 0, 0);
}
__device__ __forceinline__ void bar() { __builtin_amdgcn_s_barrier(); }
template <int Nw> __device__ __forceinline__ void waitvm() {
  if constexpr (Nw == 8)      asm volatile("s_waitcnt vmcnt(8)" ::: "memory");
  else if constexpr (Nw == 6) asm volatile("s_waitcnt vmcnt(6)" ::: "memory");
  else if constexpr (Nw == 4) asm volatile("s_waitcnt vmcnt(4)" ::: "memory");
  else                        asm volatile("s_waitcnt vmcnt(0)" ::: "memory");
}
// Phase brackets (R5/R6 skeleton — best measured).
__device__ __forceinline__ void phase_open() {
  asm volatile("" ::: "memory");
  __builtin_amdgcn_s_barrier();
  asm volatile("" ::: "memory");
  __builtin_amdgcn_s_setprio(1);
}
__device__ __forceinline__ void phase_close() {
  __builtin_amdgcn_s_setprio(0);
  asm volatile("" ::: "memory");
  __builtin_amdgcn_s_barrier();
  asm volatile("" ::: "memory");
}
template <int NV> __device__ __forceinline__ void phase_close_vm() {
  __builtin_amdgcn_s_setprio(0);
  asm volatile("" ::: "memory");
  waitvm<NV>();                 // counted drain BEFORE the barrier -> collective
  __builtin_amdgcn_s_barrier();
  asm volatile("" ::: "memory");
}

// ---------- prep kernels (R13 vectorized versions) ----------
__global__ void convert4(const float* __restrict__ in, u16* __restrict__ out) {
  int i = blockIdx.x * blockDim.x + threadIdx.x;
  float4 v = reinterpret_cast<const float4*>(in)[i];
  ushort4 o;
  o.x = f2bf(v.x); o.y = f2bf(v.y); o.z = f2bf(v.z); o.w = f2bf(v.w);
  reinterpret_cast<ushort4*>(out)[i] = o;
}

// in: [R][Cd] fp32 -> out: [Cd][R] bf16. 64x64 tile, 256 threads, 16B ops.
__global__ __launch_bounds__(256) void transpose_f32_bf16(const float* __restrict__ in,
                                                          u16* __restrict__ out,
                                                          int R, int Cd) {
  __shared__ float tile[64][65];
  int c0 = blockIdx.x * 64, r0 = blockIdx.y * 64;
  int tid = threadIdx.x;
  int c4 = tid & 15, rr = tid >> 4;
#pragma unroll
  for (int p = 0; p < 4; ++p) {
    float4 v = *reinterpret_cast<const float4*>(
        in + (size_t)(r0 + rr + 16 * p) * Cd + c0 + c4 * 4);
    tile[rr + 16 * p][c4 * 4 + 0] = v.x;
    tile[rr + 16 * p][c4 * 4 + 1] = v.y;
    tile[rr + 16 * p][c4 * 4 + 2] = v.z;
    tile[rr + 16 * p][c4 * 4 + 3] = v.w;
  }
  __syncthreads();
  int rx8 = tid & 7, cr = tid >> 3;
#pragma unroll
  for (int p = 0; p < 2; ++p) {
    int c = cr + 32 * p;
    u16x8 o;
#pragma unroll
    for (int k = 0; k < 8; ++k) o[k] = f2bf(tile[rx8 * 8 + k][c]);
    *reinterpret_cast<u16x8*>(out + (size_t)(c0 + c) * R + r0 + rx8 * 8) = o;
  }
}

// rope table: [2048][64] of (cos, sin)
__global__ void rope_table(float2* __restrict__ tab) {
  int i = blockIdx.x * blockDim.x + threadIdx.x;   // 2048*64
  int s = i >> 6, d2 = i & 63;
  float inv = powf(10000.f, -(float)d2 * (1.f / 64.f));
  float fr = (float)s * inv;
  tab[i] = make_float2(cosf(fr), sinf(fr));
}

// in-place rope, vectorized 16B (R13).
__global__ __launch_bounds__(256) void rope_apply(u16* __restrict__ qkv,
                                                  const float2* __restrict__ tab) {
  int i = blockIdx.x * blockDim.x + threadIdx.x;   // 4096*40*8
  int g = i & 7;
  int head = (i >> 3) % 40;
  int row = i / 320;
  size_t base = (size_t)row * 6144 + head * 128 + g * 8;
  u16x8 a = *reinterpret_cast<const u16x8*>(qkv + base);
  u16x8 b = *reinterpret_cast<const u16x8*>(qkv + base + 64);
  const float2* cs = tab + (row & 2047) * 64 + g * 8;
  float sc = (head < 32) ? 0.12751731654059898f : 1.f;  // log2e/sqrt(128)
  u16x8 o1, o2;
#pragma unroll
  for (int q = 0; q < 8; ++q) {
    float t1 = bf2f(a[q]), t2 = bf2f(b[q]);
    float2 c2 = cs[q];
    o1[q] = f2bf((t1 * c2.x - t2 * c2.y) * sc);
    o2[q] = f2bf((t1 * c2.y + t2 * c2.x) * sc);
  }
  *reinterpret_cast<u16x8*>(qkv + base) = o1;
  *reinterpret_cast<u16x8*>(qkv + base + 64) = o2;
}

// vT[b][hkv][d][s_perm] <- qkv[b*2048+s][5120 + hkv*128 + d]
__global__ void build_vT(const u16* __restrict__ qkv, u16* __restrict__ vT) {
  __shared__ u16 tile[32][33];
  int st = blockIdx.x, dt = blockIdx.y, bh = blockIdx.z;  // bh = b*8+hkv
  int b = bh >> 3, hkv = bh & 7;
  int tx = threadIdx.x, ty = threadIdx.y;
  int s0 = st * 32, d0 = dt * 32;
#pragma unroll
  for (int i = 0; i < 4; ++i)
    tile[ty + 8 * i][tx] =
        qkv[(size_t)(b * 2048 + s0 + ty + 8 * i) * 6144 + 5120 + hkv * 128 + d0 + tx];
  __syncthreads();
  int s = s0 + tx;
  int sl = s & 63;
  int sp = (s & ~63) | (sl & 0x23) | ((sl & 0x0C) << 1) | ((sl & 0x10) >> 2);
#pragma unroll
  for (int i = 0; i < 4; ++i)
    vT[((size_t)bh * 128 + d0 + ty + 8 * i) * 2048 + sp] = tile[tx][ty + 8 * i];
}

// ---------- GEMM1 (qkv): 256x128 tile, ring-3 LDS, 2 phases/K-tile ----------
// 8 waves 4M x 2N (wave tile 64x64), 16x16x32 MFMA. 881 TF measured, 0 conflicts.
template <int OUT_BF16>
__global__ __launch_bounds__(512, 2) void gemm_g1(const u16* __restrict__ A,
                                                  const u16* __restrict__ BT,
                                                  void* __restrict__ Cv,
                                                  int M, int N, int K) {
  __shared__ u16 As[3][256][64];
  __shared__ u16 Bs[3][128][64];
  const int tid = threadIdx.x, lane = tid & 63, wave = tid >> 6;
  const int lr = lane & 15, lg = lane >> 4, l7 = lane & 7;
  const int wm = wave >> 1, wn = wave & 1;
  const int nbx = N / 128;
  int bid = blockIdx.x;
  const int cpx = (int)gridDim.x >> 3;
  bid = (bid & 7) * cpx + (bid >> 3);               // XCD swizzle (grid%8==0)
  const int bm = (bid / nbx) * 256, bn = (bid % nbx) * 128;
  const int NT = K / 64;
  const int ch0 = (lg ^ l7) << 3, ch1 = ((4 | lg) ^ l7) << 3;

  auto stageA = [&](int t, int rg) {
    int k0 = t * 64;
#pragma unroll
    for (int o = 0; o < 4; ++o) {
      int cid = o * 512 + tid;
      int row = cid >> 3;
      int sc2 = (cid & 7) ^ (row & 7);
      load_lds16(A + (size_t)(bm + row) * K + k0 + sc2 * 8,
                 (u16*)&As[rg][0][0] + (o * 512 + wave * 64) * 8);
    }
  };
  auto stageB = [&](int t, int rg) {
    int k0 = t * 64;
#pragma unroll
    for (int o = 0; o < 2; ++o) {
      int cid = o * 512 + tid;
      int row = cid >> 3;
      int sc2 = (cid & 7) ^ (row & 7);
      load_lds16(BT + (size_t)(bn + row) * K + k0 + sc2 * 8,
                 (u16*)&Bs[rg][0][0] + (o * 512 + wave * 64) * 8);
    }
  };

  bf16x8 af[4][2], b01[2][2], b23[2][2];
  f32x4 acc[4][4] = {};

  stageB(0, 0); stageA(0, 0); stageB(1, 1); stageA(1, 1);
  waitvm<6>();
  bar();

  int c = 0;
  for (int t = 0; t < NT; ++t) {
    int cs = c + 2; if (cs >= 3) cs -= 3;
    const bool pf = (t + 2) < NT;
    // ---- P0: read A(8) + B01(4) of buf c; stage B(t+2); MFMA A x B01
#pragma unroll
    for (int mi = 0; mi < 4; ++mi) {
      af[mi][0] = *(const bf16x8*)&As[c][wm * 64 + mi * 16 + lr][ch0];
      af[mi][1] = *(const bf16x8*)&As[c][wm * 64 + mi * 16 + lr][ch1];
    }
#pragma unroll
    for (int j = 0; j < 2; ++j) {
      b01[j][0] = *(const bf16x8*)&Bs[c][wn * 64 + j * 16 + lr][ch0];
      b01[j][1] = *(const bf16x8*)&Bs[c][wn * 64 + j * 16 + lr][ch1];
    }
    if (pf) stageB(t + 2, cs);
    phase_open();
#pragma unroll
    for (int mi = 0; mi < 4; ++mi)
#pragma unroll
      for (int j = 0; j < 2; ++j) {
        acc[mi][j] = mfma16(af[mi][0], b01[j][0], acc[mi][j]);
        acc[mi][j] = mfma16(af[mi][1], b01[j][1], acc[mi][j]);
      }
    phase_close();
    // ---- P1: read B23(4); stage A(t+2); MFMA A x B23; vmcnt(6)
#pragma unroll
    for (int j = 0; j < 2; ++j) {
      b23[j][0] = *(const bf16x8*)&Bs[c][wn * 64 + (j + 2) * 16 + lr][ch0];
      b23[j][1] = *(const bf16x8*)&Bs[c][wn * 64 + (j + 2) * 16 + lr][ch1];
    }
    if (pf) stageA(t + 2, cs);
    phase_open();
#pragma unroll
    for (int mi = 0; mi < 4; ++mi)
#pragma unroll
      for (int j = 0; j < 2; ++j) {
        acc[mi][j + 2] = mfma16(af[mi][0], b23[j][0], acc[mi][j + 2]);
        acc[mi][j + 2] = mfma16(af[mi][1], b23[j][1], acc[mi][j + 2]);
      }
    if (pf) phase_close_vm<6>(); else phase_close_vm<0>();
    c = c + 1; if (c >= 3) c -= 3;
  }
#pragma unroll
  for (int mi = 0; mi < 4; ++mi) {
    int row = bm + wm * 64 + mi * 16 + lg * 4;
#pragma unroll
    for (int j = 0; j < 4; ++j) {
      int col = bn + wn * 64 + j * 16 + lr;
#pragma unroll
      for (int r = 0; r < 4; ++r) {
        if constexpr (OUT_BF16)
          ((u16*)Cv)[(size_t)(row + r) * N + col] = f2bf(acc[mi][j][r]);
        else
          ((float*)Cv)[(size_t)(row + r) * N + col] = acc[mi][j][r];
      }
    }
  }
}

// ---------- GEMM2 (out-proj): 256x256, dbuf-2, 4 phases/K-tile ----------
// R5/R6 measured config. stage(t+2) -> CURRENT buffer after barrier-retired
// reads (Bh0@P2, Bh1+A@P3); vmcnt(8) at P3-close drains stage(t+1).
template <int OUT_BF16>
__global__ __launch_bounds__(512, 2) void gemm_g2(const u16* __restrict__ A,
                                                  const u16* __restrict__ BT,
                                                  void* __restrict__ Cv,
                                                  int M, int N, int K) {
  __shared__ u16 As[2][256][64];
  __shared__ u16 Bs[2][256][64];
  const int tid = threadIdx.x, lane = tid & 63, wave = tid >> 6;
  const int lr = lane & 15, lg = lane >> 4, l7 = lane & 7;
  const int wm = wave >> 2, wn = wave & 3;
  const int nbx = N / 256;
  int bid = blockIdx.x;
  const int cpx = (int)gridDim.x >> 3;
  bid = (bid & 7) * cpx + (bid >> 3);
  const int bm = (bid / nbx) * 256, bn = (bid % nbx) * 256;
  const int NT = K / 64;
  const int ch0 = (lg ^ l7) << 3, ch1 = ((4 | lg) ^ l7) << 3;

  auto stageA = [&](int t, int rg) {
    int k0 = t * 64;
#pragma unroll
    for (int o = 0; o < 4; ++o) {
      int cid = o * 512 + tid;
      int row = cid >> 3;
      int sc2 = (cid & 7) ^ (row & 7);
      load_lds16(A + (size_t)(bm + row) * K + k0 + sc2 * 8,
                 (u16*)&As[rg][0][0] + (o * 512 + wave * 64) * 8);
    }
  };
  auto stageBh = [&](int t, int rg, int h) {
    int k0 = t * 64;
#pragma unroll
    for (int o = 0; o < 2; ++o) {
      int oo = h * 2 + o;
      int cid = oo * 512 + tid;
      int row = cid >> 3;
      int sc2 = (cid & 7) ^ (row & 7);
      load_lds16(BT + (size_t)(bn + row) * K + k0 + sc2 * 8,
                 (u16*)&Bs[rg][0][0] + (oo * 512 + wave * 64) * 8);
    }
  };

  bf16x8 a0[4][2], a1[4][2], b01[2][2], b23[2][2];
  f32x4 acc[8][4] = {};

  stageA(0, 0); stageBh(0, 0, 0); stageBh(0, 0, 1); stageA(1, 1);
  stageBh(1, 1, 0); stageBh(1, 1, 1);
  waitvm<8>();
  bar();

  for (int t = 0; t < NT; ++t) {
    const int c = t & 1;
    const bool pf = (t + 2) < NT;
    // ---- P0: read A0(8) + B01(4); MFMA A0 x B01
#pragma unroll
    for (int mi = 0; mi < 4; ++mi) {
      a0[mi][0] = *(const bf16x8*)&As[c][wm * 128 + mi * 16 + lr][ch0];
      a0[mi][1] = *(const bf16x8*)&As[c][wm * 128 + mi * 16 + lr][ch1];
    }
#pragma unroll
    for (int j = 0; j < 2; ++j) {
      b01[j][0] = *(const bf16x8*)&Bs[c][wn * 64 + j * 16 + lr][ch0];
      b01[j][1] = *(const bf16x8*)&Bs[c][wn * 64 + j * 16 + lr][ch1];
    }
    phase_open();
#pragma unroll
    for (int mi = 0; mi < 4; ++mi)
#pragma unroll
      for (int j = 0; j < 2; ++j) {
        acc[mi][j] = mfma16(a0[mi][0], b01[j][0], acc[mi][j]);
        acc[mi][j] = mfma16(a0[mi][1], b01[j][1], acc[mi][j]);
      }
    phase_close();
    // ---- P1: read B23(4); MFMA A0 x B23
#pragma unroll
    for (int j = 0; j < 2; ++j) {
      b23[j][0] = *(const bf16x8*)&Bs[c][wn * 64 + (j + 2) * 16 + lr][ch0];
      b23[j][1] = *(const bf16x8*)&Bs[c][wn * 64 + (j + 2) * 16 + lr][ch1];
    }
    phase_open();
#pragma unroll
    for (int mi = 0; mi < 4; ++mi)
#pragma unroll
      for (int j = 0; j < 2; ++j) {
        acc[mi][j + 2] = mfma16(a0[mi][0], b23[j][0], acc[mi][j + 2]);
        acc[mi][j + 2] = mfma16(a0[mi][1], b23[j][1], acc[mi][j + 2]);
      }
    phase_close();
    // ---- P2: read A1(8); stage Bh0(t+2); MFMA A1 x B01
#pragma unroll
    for (int mi = 0; mi < 4; ++mi) {
      a1[mi][0] = *(const bf16x8*)&As[c][wm * 128 + 64 + mi * 16 + lr][ch0];
      a1[mi][1] = *(const bf16x8*)&As[c][wm * 128 + 64 + mi * 16 + lr][ch1];
    }
    if (pf) stageBh(t + 2, c, 0);
    phase_open();
#pragma unroll
    for (int mi = 0; mi < 4; ++mi)
#pragma unroll
      for (int j = 0; j < 2; ++j) {
        acc[mi + 4][j] = mfma16(a1[mi][0], b01[j][0], acc[mi + 4][j]);
        acc[mi + 4][j] = mfma16(a1[mi][1], b01[j][1], acc[mi + 4][j]);
      }
    phase_close();
    // ---- P3: stage Bh1(t+2)+A(t+2); MFMA A1 x B23; vmcnt(8)
    if (pf) { stageBh(t + 2, c, 1); stageA(t + 2, c); }
    phase_open();
#pragma unroll
    for (int mi = 0; mi < 4; ++mi)
#pragma unroll
      for (int j = 0; j < 2; ++j) {
        acc[mi + 4][j + 2] = mfma16(a1[mi][0], b23[j][0], acc[mi + 4][j + 2]);
        acc[mi + 4][j + 2] = mfma16(a1[mi][1], b23[j][1], acc[mi + 4][j + 2]);
      }
    if (pf) phase_close_vm<8>(); else phase_close_vm<0>();
  }
#pragma unroll
  for (int mi = 0; mi < 8; ++mi) {
    int row = bm + wm * 128 + mi * 16 + lg * 4;
#pragma unroll
    for (int j = 0; j < 4; ++j) {
      int col = bn + wn * 64 + j * 16 + lr;
#pragma unroll
      for (int r = 0; r < 4; ++r) {
        if constexpr (OUT_BF16)
          ((u16*)Cv)[(size_t)(row + r) * N + col] = f2bf(acc[mi][j][r]);
        else
          ((float*)Cv)[(size_t)(row + r) * N + col] = acc[mi][j][r];
      }
    }
  }
}

// ---------- flash attention (no-max softmax, in-register P) ----------
// R6 version (best measured). grid (16,32,2), 4 waves; wave owns 32 q-rows.
__global__ __launch_bounds__(256, 3) void attn_fused(const u16* __restrict__ qkv,
                                                     const u16* __restrict__ vT,
                                                     u16* __restrict__ attn_out) {
  __shared__ u16 Ksm[64][128];    // [kv][d]  16 chunks/row, XOR-swizzled
  __shared__ u16 Vsm[128][64];    // [d][kv]   8 chunks/row, XOR-swizzled
  const int qt = blockIdx.x, h = blockIdx.y, b = blockIdx.z;
  const int hkv = h >> 2;
  const int tid = threadIdx.x, lane = tid & 63, wave = tid >> 6;
  const int lr = lane & 15, lg = lane >> 4;
  const int qrow0 = qt * 128 + wave * 32;

  bf16x8 qf[2][4];
#pragma unroll
  for (int q2 = 0; q2 < 2; ++q2) {
    const u16* qp = qkv + (size_t)(b * 2048 + qrow0 + q2 * 16 + lr) * 6144 + h * 128;
#pragma unroll
    for (int kk = 0; kk < 4; ++kk)
      qf[q2][kk] = *(const bf16x8*)(qp + kk * 32 + lg * 8);
  }
  float l_acc[2] = {0.f, 0.f};
  f32x4 acc_o[2][8] = {};

  for (int kv0 = 0; kv0 < 2048; kv0 += 64) {
#pragma unroll
    for (int c = 0; c < 4; ++c) {
      int cid = c * 256 + tid;
      int base = (c * 256 + wave * 64) * 8;
      int krow = cid >> 4;
      int kcc = (cid & 15) ^ (krow & 7);
      load_lds16(qkv + (size_t)(b * 2048 + kv0 + krow) * 6144 + 4096 + hkv * 128 + kcc * 8,
                 (u16*)Ksm + base);
      int vrow = cid >> 3;
      int vcc = (cid & 7) ^ (vrow & 7);
      load_lds16(vT + ((size_t)(b * 8 + hkv) * 128 + vrow) * 2048 + kv0 + vcc * 8,
                 (u16*)Vsm + base);
    }
    __syncthreads();

    bf16x8 pfr[2][2];
#pragma unroll
    for (int k2 = 0; k2 < 2; ++k2) {
      f32x4 sc[2][2] = {};
#pragma unroll
      for (int ktl = 0; ktl < 2; ++ktl) {
        int krow = (k2 * 2 + ktl) * 16 + lr;
#pragma unroll
        for (int kk = 0; kk < 4; ++kk) {
          bf16x8 kf = *(const bf16x8*)((u16*)Ksm + krow * 128 +
                                       ((((kk << 2) | lg) ^ (krow & 7)) << 3));
          sc[0][ktl] = mfma16(kf, qf[0][kk], sc[0][ktl]);
          sc[1][ktl] = mfma16(kf, qf[1][kk], sc[1][ktl]);
        }
      }
#pragma unroll
      for (int q2 = 0; q2 < 2; ++q2) {
        bf16x8 pk;
#pragma unroll
        for (int ktl = 0; ktl < 2; ++ktl)
#pragma unroll
          for (int r = 0; r < 4; ++r) {
            float e = exp2_hw(sc[q2][ktl][r]);
            l_acc[q2] += e;
            pk[ktl * 4 + r] = (__bf16)e;
          }
        pfr[q2][k2] = pk;
      }
    }
#pragma unroll
    for (int dt = 0; dt < 8; ++dt) {
      int vrow = dt * 16 + lr;
#pragma unroll
      for (int k2 = 0; k2 < 2; ++k2) {
        bf16x8 vf = *(const bf16x8*)((u16*)Vsm + vrow * 64 +
                                     ((((k2 << 2) | lg) ^ (vrow & 7)) << 3));
        acc_o[0][dt] = mfma16(pfr[0][k2], vf, acc_o[0][dt]);
        acc_o[1][dt] = mfma16(pfr[1][k2], vf, acc_o[1][dt]);
      }
    }
    __syncthreads();
  }
#pragma unroll
  for (int q2 = 0; q2 < 2; ++q2) {
    float l = l_acc[q2];
    l += __shfl_xor(l, 16);
    l += __shfl_xor(l, 32);
    float li = 1.f / l;
    float linv[4];
#pragma unroll
    for (int r = 0; r < 4; ++r) linv[r] = __shfl(li, lg * 4 + r);
    u16* op = attn_out + (size_t)(b * 2048 + qrow0 + q2 * 16) * 4096 + h * 128;
#pragma unroll
    for (int dt = 0; dt < 8; ++dt)
#pragma unroll
      for (int r = 0; r < 4; ++r)
        op[(size_t)(lg * 4 + r) * 4096 + dt * 16 + lr] = f2bf(acc_o[q2][dt][r] * linv[r]);
  }
}

// ---------- launch ----------
extern "C" void kernel_launch(void* const* d_in, const int* in_sizes, int n_in,
                              void* d_out, int out_size, void* d_ws, size_t ws_size,
                              hipStream_t stream) {
  const float* x     = (const float*)d_in[0];   // [2][2048][4096]
  const float* w_qkv = (const float*)d_in[1];   // [4096][6144]
  const float* w_out = (const float*)d_in[2];   // [4096][4096]
  float* out = (float*)d_out;                   // [4096][4096] fp32
  char* ws = (char*)d_ws;

  u16*    xbf = (u16*)(ws);                         // 32MB; later reused as attn_out
  u16*    wT  = (u16*)(ws + (size_t)33554432);      // 48MB; wqkvT then woutT
  u16*    qkv = (u16*)(ws + (size_t)83886080);      // 48MB
  u16*    vT  = (u16*)(ws + (size_t)134217728);     // 8MB
  float2* tab = (float2*)(ws + (size_t)142606336);  // 1MB

  dim3 tb(32, 8);
  convert4<<<16384, 256, 0, stream>>>(x, xbf);
  transpose_f32_bf16<<<dim3(96, 64), 256, 0, stream>>>(w_qkv, wT, 4096, 6144);
  rope_table<<<512, 256, 0, stream>>>(tab);
  // qkv = xbf @ wT^T : M=4096, N=6144, K=4096.  768 wgs = 3 full CU rounds
  gemm_g1<1><<<768, 512, 0, stream>>>(xbf, wT, qkv, 4096, 6144, 4096);
  rope_apply<<<5120, 256, 0, stream>>>(qkv, tab);
  build_vT<<<dim3(64, 4, 16), tb, 0, stream>>>(qkv, vT);
  attn_fused<<<dim3(16, 32, 2), 256, 0, stream>>>(qkv, vT, xbf);
  transpose_f32_bf16<<<dim3(64, 64), 256, 0, stream>>>(w_out, wT, 4096, 4096);
  // out = attn @ woutT^T : M=N=K=4096.  256 wgs = exactly 1 round
  gemm_g2<0><<<256, 512, 0, stream>>>(xbf, wT, out, 4096, 4096, 4096);
}